// Round 3
// baseline (259.228 us; speedup 1.0000x reference)
//
#include <hip/hip_runtime.h>
#include <math.h>

#define N_ROWS 131072
#define DIM 64
#define KCODES 512
#define ROWS_PER_BLOCK 64
#define KCHUNK 64
#define LDS_STRIDE 68   // multiple of 4 (16B-aligned b128 rows); stride mod 32 = 4 keeps conflicts mild

// float-element offsets into d_out (concatenated outputs, all read back as f32)
#define O_LOSS 0
#define O_Q    1ull
#define O_PERP 8388609ull
#define O_ENC  8388610ull
#define O_IDX  75497474ull

// ---- numpy pairwise-sum (n=64, scalar 8-accumulator path) of squares, fp-contract OFF ----
// r[j] = ((fl(a[j]^2) + fl(a[j+8]^2)) + ... sequential); res = ((r0+r1)+(r2+r3))+((r4+r5)+(r6+r7))

// ---------------- prep: zero accumulators, ||e_k||^2 in numpy order ----------------
__global__ void vq_prep(const float* __restrict__ emb, float* __restrict__ bsq,
                        int* __restrict__ counts, double* __restrict__ loss_acc) {
#pragma clang fp contract(off)
    int c = blockIdx.x * blockDim.x + threadIdx.x;
    if (c < KCODES) {
        const float* e = emb + (size_t)c * DIM;
        float r[8];
#pragma unroll
        for (int j = 0; j < 8; ++j) { float v = e[j]; r[j] = v * v; }
#pragma unroll
        for (int i = 8; i < 64; i += 8)
#pragma unroll
            for (int j = 0; j < 8; ++j) { float v = e[i + j]; r[j] = r[j] + v * v; }
        bsq[c] = ((r[0] + r[1]) + (r[2] + r[3])) + ((r[4] + r[5]) + (r[6] + r[7]));
        counts[c] = 0;
    }
    if (blockIdx.x == 0 && threadIdx.x == 0) *loss_acc = 0.0;
}

// ---------------- main fused kernel ----------------
__global__ __launch_bounds__(256, 4) void vq_main(
    const float* __restrict__ x, const float* __restrict__ emb,
    const float* __restrict__ bsq, int* __restrict__ counts,
    double* __restrict__ loss_acc, float* __restrict__ out)
{
#pragma clang fp contract(off)
    __shared__ float Xt[DIM * LDS_STRIDE];     // Xt[d*68 + r]  (r = row in tile)
    __shared__ float Et[DIM * LDS_STRIDE];     // Et[d*68 + c]  (c = code in chunk)
    __shared__ float sx_lds[ROWS_PER_BLOCK];   // numpy-order ||x_r||^2
    __shared__ int   idx_lds[ROWS_PER_BLOCK];
    __shared__ double wsum[4];

    const int tid  = threadIdx.x;
    const int row0 = blockIdx.x * ROWS_PER_BLOCK;
    const int tx   = tid & 15;   // code group (4 codes)
    const int ty   = tid >> 4;   // row group  (4 rows)

    // ---- stage X tile transposed: Xt[d][r] ----
#pragma unroll
    for (int k = 0; k < 16; ++k) {
        int i = tid + k * 256;           // 0..4095
        int r = i >> 6, d = i & 63;
        Xt[d * LDS_STRIDE + r] = x[(size_t)(row0 + r) * DIM + d];
    }
    __syncthreads();

    // ---- ||x||^2 per row, numpy pairwise order (squares rounded, no fma) ----
    if (tid < ROWS_PER_BLOCK) {
        float r[8];
#pragma unroll
        for (int j = 0; j < 8; ++j) { float v = Xt[j * LDS_STRIDE + tid]; r[j] = v * v; }
#pragma unroll
        for (int i = 8; i < 64; i += 8)
#pragma unroll
            for (int j = 0; j < 8; ++j) { float v = Xt[(i + j) * LDS_STRIDE + tid]; r[j] = r[j] + v * v; }
        sx_lds[tid] = ((r[0] + r[1]) + (r[2] + r[3])) + ((r[4] + r[5]) + (r[6] + r[7]));
    }

    float m1v[4];
    int   i1[4];
#pragma unroll
    for (int m = 0; m < 4; ++m) { m1v[m] = 3.4e38f; i1[m] = 0; }

    for (int ch = 0; ch < KCODES / KCHUNK; ++ch) {
        if (ch > 0) __syncthreads();     // Et safe to overwrite
#pragma unroll
        for (int k = 0; k < 16; ++k) {
            int i = tid + k * 256;
            int c = i >> 6, d = i & 63;
            Et[d * LDS_STRIDE + c] = emb[(size_t)(ch * KCHUNK + c) * DIM + d];
        }
        __syncthreads();                 // Et (and, at ch=0, sx_lds) visible

        float acc[4][4];
#pragma unroll
        for (int m = 0; m < 4; ++m)
#pragma unroll
            for (int n = 0; n < 4; ++n) acc[m][n] = 0.f;

        // sequential-k FMA chain, ascending d — bit-matches BLAS sgemm microkernel
#pragma unroll 8
        for (int d = 0; d < DIM; ++d) {
            float4 a = *reinterpret_cast<const float4*>(&Xt[d * LDS_STRIDE + ty * 4]);
            float4 b = *reinterpret_cast<const float4*>(&Et[d * LDS_STRIDE + tx * 4]);
            float av[4] = {a.x, a.y, a.z, a.w};
            float bv[4] = {b.x, b.y, b.z, b.w};
#pragma unroll
            for (int m = 0; m < 4; ++m)
#pragma unroll
                for (int n = 0; n < 4; ++n)
                    acc[m][n] = fmaf(av[m], bv[n], acc[m][n]);
        }

        const int cbase = ch * KCHUNK + tx * 4;
        float4 bsv = *reinterpret_cast<const float4*>(&bsq[cbase]);
        float bs[4] = {bsv.x, bsv.y, bsv.z, bsv.w};
#pragma unroll
        for (int m = 0; m < 4; ++m) {
            float sxm = sx_lds[ty * 4 + m];
#pragma unroll
            for (int n = 0; n < 4; ++n) {
                // d = fl(fl(sx + se) - 2*dot)  — exactly the reference's f32 rounding
                float S  = sxm + bs[n];
                float dd = S - 2.0f * acc[m][n];
                if (dd < m1v[m]) { m1v[m] = dd; i1[m] = cbase + n; }   // strict <: first-occurrence
            }
        }
    }

    // ---- reduce (min, argmin) across the 16 tx lanes; ties -> lowest index ----
#pragma unroll
    for (int off = 8; off >= 1; off >>= 1) {
#pragma unroll
        for (int m = 0; m < 4; ++m) {
            float ov = __shfl_xor(m1v[m], off, 64);
            int   oi = __shfl_xor(i1[m],  off, 64);
            if (ov < m1v[m] || (ov == m1v[m] && oi < i1[m])) { m1v[m] = ov; i1[m] = oi; }
        }
    }

    if (tx == 0) {
#pragma unroll
        for (int m = 0; m < 4; ++m) {
            int r = ty * 4 + m;
            idx_lds[r] = i1[m];
            out[O_IDX + row0 + r] = (float)i1[m];
            atomicAdd(&counts[i1[m]], 1);
        }
    }
    __syncthreads();

    // ---- quantized_st + loss partial ----
    double lsum = 0.0;
#pragma unroll
    for (int kq = 0; kq < 16; ++kq) {
        int i = tid + kq * 256;          // 0..4095
        int r = i >> 6, d = i & 63;
        int id = idx_lds[r];
        float xv = Xt[d * LDS_STRIDE + r];
        float ev = emb[(size_t)id * DIM + d];
        float diff = ev - xv;                                 // quantized - inputs (f32, same as ref)
        out[O_Q + (size_t)(row0 + r) * DIM + d] = xv + diff;  // straight-through value
        lsum += (double)diff * (double)diff;
    }

    // ---- one-hot encodings tile (64 rows x 512 codes) as float2 ----
    float2* enc2 = reinterpret_cast<float2*>(out + O_ENC + (size_t)row0 * KCODES);
#pragma unroll 4
    for (int ke = 0; ke < 64; ++ke) {
        int i = tid + ke * 256;          // 0..16383 float2s
        int r = i >> 8;                  // 256 float2 per row
        int c = (i & 255) * 2;
        int id = idx_lds[r];
        float2 v;
        v.x = (c     == id) ? 1.f : 0.f;
        v.y = (c + 1 == id) ? 1.f : 0.f;
        enc2[i] = v;
    }

    // ---- block-reduce loss, one f64 atomic per block ----
#pragma unroll
    for (int off = 32; off >= 1; off >>= 1) lsum += __shfl_xor(lsum, off, 64);
    if ((tid & 63) == 0) wsum[tid >> 6] = lsum;
    __syncthreads();
    if (tid == 0) atomicAdd(loss_acc, wsum[0] + wsum[1] + wsum[2] + wsum[3]);
}

// ---------------- finalize: scalars ----------------
__global__ void vq_fin(const int* __restrict__ counts, const double* __restrict__ loss_acc,
                       float* __restrict__ out) {
    int t = threadIdx.x;     // 256
    double h = 0.0;
    for (int c = t; c < KCODES; c += 256) {
        double p = (double)counts[c] / (double)N_ROWS;
        h += p * log(p + 1e-10);
    }
#pragma unroll
    for (int off = 32; off >= 1; off >>= 1) h += __shfl_xor(h, off, 64);
    __shared__ double ws[4];
    if ((t & 63) == 0) ws[t >> 6] = h;
    __syncthreads();
    if (t == 0) {
        double H = ws[0] + ws[1] + ws[2] + ws[3];
        out[O_PERP] = (float)exp(-H);
        out[O_LOSS] = (float)(1.25 * (*loss_acc) / (double)(N_ROWS * DIM));
    }
}

extern "C" void kernel_launch(void* const* d_in, const int* in_sizes, int n_in,
                              void* d_out, int out_size, void* d_ws, size_t ws_size,
                              hipStream_t stream) {
    const float* x   = (const float*)d_in[0];
    const float* emb = (const float*)d_in[1];
    float* out = (float*)d_out;

    // workspace: [0,2048) f32 bsq | [2048,4096) int counts | 4096 double loss
    float*  bsq      = (float*)d_ws;
    int*    counts   = (int*)((char*)d_ws + 2048);
    double* loss_acc = (double*)((char*)d_ws + 4096);

    vq_prep<<<2, 256, 0, stream>>>(emb, bsq, counts, loss_acc);
    vq_main<<<N_ROWS / ROWS_PER_BLOCK, 256, 0, stream>>>(x, emb, bsq, counts, loss_acc, out);
    vq_fin<<<1, 256, 0, stream>>>(counts, loss_acc, out);
}

// Round 4
// 179.067 us; speedup vs baseline: 1.4477x; 1.4477x over previous
//
#include <hip/hip_runtime.h>
#include <math.h>

#define N_ROWS 131072
#define DIM 64
#define KCODES 512
#define RPB 128               // rows per block
#define KCHUNK 128            // codes per chunk
#define NCHUNK (KCODES / KCHUNK)

// float-element offsets into d_out (concatenated outputs, all read back as f32)
#define O_LOSS 0
#define O_Q    1ull
#define O_PERP 8388609ull
#define O_ENC  8388610ull
#define O_IDX  75497474ull

// Swizzled flat LDS address for a [rows][64 floats] tile: 16B-granule XOR keeps
// both the 8-row (a) and 8-code (b) fragment reads conflict-free.
__device__ __forceinline__ int swz(int row, int gran) {
    return row * 64 + ((gran ^ ((row >> 3) & 15)) << 2);
}

// ---------------- prep: zero accumulators, ||e_k||^2 in numpy pairwise order ----------------
__global__ void vq_prep(const float* __restrict__ emb, float* __restrict__ bsq,
                        int* __restrict__ counts, double* __restrict__ loss_acc) {
#pragma clang fp contract(off)
    int c = blockIdx.x * blockDim.x + threadIdx.x;
    if (c < KCODES) {
        const float* e = emb + (size_t)c * DIM;
        float r[8];
#pragma unroll
        for (int j = 0; j < 8; ++j) { float v = e[j]; r[j] = v * v; }
#pragma unroll
        for (int i = 8; i < 64; i += 8)
#pragma unroll
            for (int j = 0; j < 8; ++j) { float v = e[i + j]; r[j] = r[j] + v * v; }
        bsq[c] = ((r[0] + r[1]) + (r[2] + r[3])) + ((r[4] + r[5]) + (r[6] + r[7]));
        counts[c] = 0;
    }
    if (blockIdx.x == 0 && threadIdx.x == 0) *loss_acc = 0.0;
}

// ---------------- main fused kernel: 128x512, 8x8 register tile ----------------
__global__ __launch_bounds__(256, 2) void vq_main(
    const float* __restrict__ x, const float* __restrict__ emb,
    const float* __restrict__ bsq, int* __restrict__ counts,
    double* __restrict__ loss_acc, float* __restrict__ out)
{
#pragma clang fp contract(off)
    __shared__ __align__(16) float Xt[RPB * DIM];      // swizzled [row][d]
    __shared__ __align__(16) float Et[KCHUNK * DIM];   // swizzled [code][d]
    __shared__ float  sx_lds[RPB];
    __shared__ int    idx_lds[RPB];
    __shared__ double wsum[4];

    const int tid  = threadIdx.x;
    const int row0 = blockIdx.x * RPB;
    const int tx   = tid & 15;   // code group (8 codes)
    const int ty   = tid >> 4;   // row group  (8 rows)

    // ---- stage X tile + first E chunk (float4 loads, swizzled LDS writes) ----
#pragma unroll
    for (int k = 0; k < 8; ++k) {
        int gi = tid + k * 256;            // granule 0..2047
        int r = gi >> 4, db = gi & 15;
        float4 v = *reinterpret_cast<const float4*>(&x[(size_t)(row0 + r) * DIM + db * 4]);
        *reinterpret_cast<float4*>(&Xt[swz(r, db)]) = v;
    }
#pragma unroll
    for (int k = 0; k < 8; ++k) {
        int gi = tid + k * 256;
        int c = gi >> 4, db = gi & 15;
        float4 v = *reinterpret_cast<const float4*>(&emb[(size_t)c * DIM + db * 4]);
        *reinterpret_cast<float4*>(&Et[swz(c, db)]) = v;
    }
    __syncthreads();

    // ---- ||x||^2 per row, numpy pairwise order; 2 threads per row ----
    {
        int r = tid >> 1, jb = (tid & 1) * 4;
        float rr[4];
#pragma unroll
        for (int j = 0; j < 4; ++j) {
            int d = jb + j;
            float v = Xt[swz(r, d >> 2) + (d & 3)];
            rr[j] = v * v;
        }
#pragma unroll
        for (int i = 8; i < 64; i += 8)
#pragma unroll
            for (int j = 0; j < 4; ++j) {
                int d = i + jb + j;
                float v = Xt[swz(r, d >> 2) + (d & 3)];
                rr[j] = rr[j] + v * v;
            }
        float s = (rr[0] + rr[1]) + (rr[2] + rr[3]);
        float o = __shfl_xor(s, 1, 64);
        if ((tid & 1) == 0) sx_lds[r] = s + o;   // ((r0+r1)+(r2+r3)) + ((r4+r5)+(r6+r7))
    }
    __syncthreads();

    float sxm[8];
#pragma unroll
    for (int m = 0; m < 8; ++m) sxm[m] = sx_lds[ty * 8 + m];

    float m1v[8]; int i1[8];
#pragma unroll
    for (int m = 0; m < 8; ++m) { m1v[m] = 3.4e38f; i1[m] = 0; }

    for (int ch = 0; ch < NCHUNK; ++ch) {
        float acc[8][8];
#pragma unroll
        for (int m = 0; m < 8; ++m)
#pragma unroll
            for (int n = 0; n < 8; ++n) acc[m][n] = 0.f;

        // sequential-k FMA chain per acc element, ascending d (bit-matches reference)
#pragma unroll 2
        for (int db = 0; db < 16; ++db) {
            float a[8][4], b[8][4];
#pragma unroll
            for (int m = 0; m < 8; ++m) {
                float4 v = *reinterpret_cast<const float4*>(&Xt[(ty * 8 + m) * 64 + ((db ^ ty) << 2)]);
                a[m][0] = v.x; a[m][1] = v.y; a[m][2] = v.z; a[m][3] = v.w;
            }
#pragma unroll
            for (int n = 0; n < 8; ++n) {
                float4 v = *reinterpret_cast<const float4*>(&Et[(tx * 8 + n) * 64 + ((db ^ tx) << 2)]);
                b[n][0] = v.x; b[n][1] = v.y; b[n][2] = v.z; b[n][3] = v.w;
            }
#pragma unroll
            for (int j = 0; j < 4; ++j)
#pragma unroll
                for (int m = 0; m < 8; ++m)
#pragma unroll
                    for (int n = 0; n < 8; ++n)
                        acc[m][n] = fmaf(a[m][j], b[n][j], acc[m][n]);
        }

        const int cbase = ch * KCHUNK + tx * 8;
        float4 b0 = *reinterpret_cast<const float4*>(&bsq[cbase]);
        float4 b1 = *reinterpret_cast<const float4*>(&bsq[cbase + 4]);
        float bs[8] = {b0.x, b0.y, b0.z, b0.w, b1.x, b1.y, b1.z, b1.w};
#pragma unroll
        for (int m = 0; m < 8; ++m)
#pragma unroll
            for (int n = 0; n < 8; ++n) {
                float S  = sxm[m] + bs[n];              // fl(sx + se)
                float dd = S - 2.0f * acc[m][n];        // fl(S - 2*dot) — exact ref rounding
                if (dd < m1v[m]) { m1v[m] = dd; i1[m] = cbase + n; }  // strict <: first occurrence
            }

        if (ch < NCHUNK - 1) {
            __syncthreads();   // everyone done reading Et
#pragma unroll
            for (int k = 0; k < 8; ++k) {
                int gi = tid + k * 256;
                int c = gi >> 4, db = gi & 15;
                float4 v = *reinterpret_cast<const float4*>(
                    &emb[(size_t)((ch + 1) * KCHUNK + c) * DIM + db * 4]);
                *reinterpret_cast<float4*>(&Et[swz(c, db)]) = v;
            }
            __syncthreads();
        }
    }

    // ---- reduce (min, argmin) across 16 tx lanes; ties -> lowest index ----
#pragma unroll
    for (int off = 8; off >= 1; off >>= 1)
#pragma unroll
        for (int m = 0; m < 8; ++m) {
            float ov = __shfl_xor(m1v[m], off, 64);
            int   oi = __shfl_xor(i1[m],  off, 64);
            if (ov < m1v[m] || (ov == m1v[m] && oi < i1[m])) { m1v[m] = ov; i1[m] = oi; }
        }

    if (tx == 0) {
#pragma unroll
        for (int m = 0; m < 8; ++m) {
            int r = ty * 8 + m;
            idx_lds[r] = i1[m];
            out[O_IDX + row0 + r] = (float)i1[m];
            atomicAdd(&counts[i1[m]], 1);
        }
    }
    __syncthreads();

    // ---- quantized_st + loss partial (scalar stores: O_Q base is odd -> unaligned) ----
    double lsum = 0.0;
#pragma unroll 4
    for (int k = 0; k < 32; ++k) {
        int i = tid + k * 256;            // 0..8191
        int r = i >> 6, d = i & 63;
        int id = idx_lds[r];
        float xv = Xt[swz(r, d >> 2) + (d & 3)];
        float ev = emb[(size_t)id * DIM + d];
        float diff = ev - xv;                                  // quantized - inputs (f32)
        out[O_Q + (size_t)(row0 + r) * DIM + d] = xv + diff;   // straight-through value
        lsum += (double)diff * (double)diff;
    }

    // ---- one-hot encodings tile (128 rows x 512 codes) as float2 ----
    float2* enc2 = reinterpret_cast<float2*>(out + O_ENC + (size_t)row0 * KCODES);
#pragma unroll 4
    for (int k = 0; k < 128; ++k) {
        int i = tid + k * 256;            // 0..32767 float2s
        int r = i >> 8;                   // 256 float2 per row
        int c = (i & 255) * 2;
        int id = idx_lds[r];
        float2 v;
        v.x = (c     == id) ? 1.f : 0.f;
        v.y = (c + 1 == id) ? 1.f : 0.f;
        enc2[i] = v;
    }

    // ---- block-reduce loss, one f64 atomic per block ----
#pragma unroll
    for (int off = 32; off >= 1; off >>= 1) lsum += __shfl_xor(lsum, off, 64);
    if ((tid & 63) == 0) wsum[tid >> 6] = lsum;
    __syncthreads();
    if (tid == 0) atomicAdd(loss_acc, wsum[0] + wsum[1] + wsum[2] + wsum[3]);
}

// ---------------- finalize: scalars ----------------
__global__ void vq_fin(const int* __restrict__ counts, const double* __restrict__ loss_acc,
                       float* __restrict__ out) {
    int t = threadIdx.x;     // 256
    double h = 0.0;
    for (int c = t; c < KCODES; c += 256) {
        double p = (double)counts[c] / (double)N_ROWS;
        h += p * log(p + 1e-10);
    }
#pragma unroll
    for (int off = 32; off >= 1; off >>= 1) h += __shfl_xor(h, off, 64);
    __shared__ double ws[4];
    if ((t & 63) == 0) ws[t >> 6] = h;
    __syncthreads();
    if (t == 0) {
        double H = ws[0] + ws[1] + ws[2] + ws[3];
        out[O_PERP] = (float)exp(-H);
        out[O_LOSS] = (float)(1.25 * (*loss_acc) / (double)(N_ROWS * DIM));
    }
}

extern "C" void kernel_launch(void* const* d_in, const int* in_sizes, int n_in,
                              void* d_out, int out_size, void* d_ws, size_t ws_size,
                              hipStream_t stream) {
    const float* x   = (const float*)d_in[0];
    const float* emb = (const float*)d_in[1];
    float* out = (float*)d_out;

    // workspace: [0,2048) f32 bsq | [2048,4096) int counts | 4096 double loss
    float*  bsq      = (float*)d_ws;
    int*    counts   = (int*)((char*)d_ws + 2048);
    double* loss_acc = (double*)((char*)d_ws + 4096);

    vq_prep<<<2, 256, 0, stream>>>(emb, bsq, counts, loss_acc);
    vq_main<<<N_ROWS / RPB, 256, 0, stream>>>(x, emb, bsq, counts, loss_acc, out);
    vq_fin<<<1, 256, 0, stream>>>(counts, loss_acc, out);
}